// Round 11
// baseline (226.733 us; speedup 1.0000x reference)
//
#include <hip/hip_runtime.h>
#include <stdint.h>

// Haar 3D DWT: float32 in, float32 out, fp32 internal math.
// x: (2,3,16,256,256) f32
// out: LLL (2,3,15,256,256) followed by detail (2,3,105,256,256), f32.
// detail frame-axis order: LLH, LHL, LHH, HLL, HLH, HHL, HHH (15 frames each).
//
// V3 (7th resubmit; rounds 4-10 were GPU-acquisition timeouts, no data):
// subband-specialized, fully linear writes.
//  - each wave computes ONE subband k for a 4-row strip -> 4x1KB contiguous
//    NT stores to a single output stream (plane-linear across blocks).
//  - XCD-bijective swizzle maps each XCD to one subband: per-XCD writes are
//    one linear ~23.6MB region (same pattern as the 6.4TB/s poison fill).
//  - reads amplified 8x but served by L2/L3 (input = 25MB, L3-resident).
//  - math identical per stage to baseline (same absmax expected).

static constexpr float S = 0.35355339059327373f;  // 1/(2*sqrt(2))
static constexpr int   PLANE = 256 * 256;          // 65536
static constexpr size_t LLL_ELEMS = (size_t)6 * 15 * PLANE;  // 5,898,240

typedef float f32x4 __attribute__((ext_vector_type(4)));

__device__ __forceinline__ void nt_store(float* p, f32x4 v) {
    __builtin_nontemporal_store(v, (f32x4*)p);
}

__global__ __launch_bounds__(256) void haar3d_sub_kernel(const float* __restrict__ x,
                                                         float* __restrict__ out) {
    // XCD-bijective swizzle (11520 % 8 == 0): XCD x owns subband x entirely.
    const int bid0 = blockIdx.x;
    const int bid  = (bid0 & 7) * 1440 + (bid0 >> 3);

    // bid = k*1440 + nc*240 + f*16 + hb
    const int k  = bid / 1440;            // subband 0..7 (LLL,LLH,LHL,LHH,HLL,HLH,HHL,HHH)
    int rem = bid - k * 1440;
    const int nc = rem / 240;             // 0..5  (n*3 + c)
    rem -= nc * 240;
    const int f  = rem >> 4;              // 0..14
    const int hb = rem & 15;              // 0..15
    const int wv = threadIdx.x >> 6;      // wave in block 0..3
    const int lane = threadIdx.x & 63;
    const int h  = ((hb << 2) + wv) << 2; // 0,4,...,252  (4-row strip)
    const int w  = lane << 2;

    const bool F  = (k >> 2) & 1;  // frame   high-pass?
    const bool Hs = (k >> 1) & 1;  // height  high-pass?
    const bool W  = k & 1;         // width   high-pass?

    // ---- loads: rows h..h+4 of frames f, f+1 (10 x float4 per thread) ----
    const float* p0 = x + ((size_t)(nc * 16 + f) * 256 + h) * 256 + w;  // frame f
    const float* p1 = p0 + PLANE;                                       // frame f+1

    f32x4 a[5], b[5];
#pragma unroll
    for (int r = 0; r < 4; ++r) {
        a[r] = *(const f32x4*)(p0 + r * 256);
        b[r] = *(const f32x4*)(p1 + r * 256);
    }
    if (h < 252) {                         // wave-uniform; row 256 is the height zero-pad
        a[4] = *(const f32x4*)(p0 + 4 * 256);
        b[4] = *(const f32x4*)(p1 + 4 * 256);
    } else {
        a[4] = (f32x4)0.f;
        b[4] = (f32x4)0.f;
    }

    // ---- frames stage + height stage ----
    // u[q][j]: height-filtered value at output row h+q, width w+j; u[q][4] via shfl.
    float u[4][5];
#pragma unroll
    for (int j = 0; j < 4; ++j) {
        float t[5];
#pragma unroll
        for (int r = 0; r < 5; ++r) {
            const float av = a[r][j];
            const float bv = b[r][j];
            t[r] = F ? S * (bv - av) : S * (av + bv);
        }
#pragma unroll
        for (int q = 0; q < 4; ++q)
            u[q][j] = Hs ? S * (t[q + 1] - t[q]) : S * (t[q] + t[q + 1]);
    }

    // ---- width neighbor (w+4) from lane+1; lane 63 -> right zero pad ----
    const bool last = (lane == 63);
#pragma unroll
    for (int q = 0; q < 4; ++q) {
        const float n = __shfl_down(u[q][0], 1);
        u[q][4] = last ? 0.f : n;
    }

    // ---- width stage + 4 contiguous NT row stores (4KB/wave, single stream) ----
    float* dst;
    if (k == 0) {
        dst = out + ((size_t)(nc * 15 + f)) * PLANE + (size_t)h * 256 + w;
    } else {
        dst = out + LLL_ELEMS +
              ((size_t)nc * 105 + (size_t)(k - 1) * 15 + f) * PLANE +
              (size_t)h * 256 + w;
    }
#pragma unroll
    for (int q = 0; q < 4; ++q) {
        f32x4 o;
        if (W) {
            o.x = S * (u[q][1] - u[q][0]);
            o.y = S * (u[q][2] - u[q][1]);
            o.z = S * (u[q][3] - u[q][2]);
            o.w = S * (u[q][4] - u[q][3]);
        } else {
            o.x = S * (u[q][0] + u[q][1]);
            o.y = S * (u[q][1] + u[q][2]);
            o.z = S * (u[q][2] + u[q][3]);
            o.w = S * (u[q][3] + u[q][4]);
        }
        nt_store(dst + q * 256, o);
    }
}

extern "C" void kernel_launch(void* const* d_in, const int* in_sizes, int n_in,
                              void* d_out, int out_size, void* d_ws, size_t ws_size,
                              hipStream_t stream) {
    const float* x = (const float*)d_in[0];
    float* out = (float*)d_out;
    // 8 subbands x 6 nc x 15 f x 16 hb = 11520 blocks of 256 (exact)
    haar3d_sub_kernel<<<dim3(11520), dim3(256), 0, stream>>>(x, out);
}